// Round 5
// baseline (204.939 us; speedup 1.0000x reference)
//
#include <hip/hip_runtime.h>
#include <hip/hip_bf16.h>

typedef __attribute__((ext_vector_type(8))) short short8;
typedef __attribute__((ext_vector_type(4))) short short4v;
typedef __attribute__((ext_vector_type(16))) float floatx16;

#define Bn 32
#define Ln 512
#define Cn 300
#define Hn 512
#define Nn (Bn*Ln)          // 16384
#define XBP 518             // 512 + 3 halo each side
#define XBC 320             // channels padded to 10*32
#define HK 1216             // 4 convs x 304 (300 + 4 pad), 16-aligned slices
#define LDSTC 72            // LDS row stride in shorts (conflict-free b128, verified r2/r3)

#define XROWS 134
#define XSZ (XROWS*LDSTC)   // 9648 shorts (x2 = 38.6 KB)

// workspace layout in bf16 elements
#define XB_ELEMS (Bn*XBP*XBC)            // 5,304,320
#define WB_ELEMS 1597440                  // (1+2+3+7)*122880, frag-major
#define WC_ELEMS (Hn*HK)                  // 622,592
#define XB_OFF 0
#define WB_OFF (XB_OFF + XB_ELEMS)
#define WC_OFF (WB_OFF + WB_ELEMS)
#define HB_OFF (WC_OFF + WC_ELEMS)

__device__ __forceinline__ float fast_tanh(float x) {
    float ax = __builtin_fabsf(x);
    float t  = __expf(-2.f * ax);
    float r  = __builtin_fmaf(-2.f * t, __frcp_rn(1.f + t), 1.f);  // (1-t)/(1+t)
    return __builtin_copysignf(r, x);
}

// ---------------- merged prep kernel ----------------
// section 1: edge-padded bf16 x [b][p][c]
// section 2: frag-major conv weights (A-operand frags: lane&31 = m, lane>>5 = k-octet)
// section 3: frag-major combined linear weight, k padded per-conv to 304
__global__ void prep_all(const float* __restrict__ x,
                         const float* __restrict__ w1, const float* __restrict__ w2,
                         const float* __restrict__ w3, const float* __restrict__ w7,
                         const float* __restrict__ slp_w,
                         __hip_bfloat16* __restrict__ wsb) {
    int idx = blockIdx.x * 256 + threadIdx.x;
    if (idx < XB_ELEMS) {
        int c = idx % XBC;
        int t = idx / XBC;
        int p = t % XBP;
        int b = t / XBP;
        int l = p - 3;
        l = l < 0 ? 0 : (l > Ln - 1 ? Ln - 1 : l);   // replication pad
        float v = (c < Cn) ? x[(b * Ln + l) * Cn + c] : 0.f;
        wsb[idx] = __float2bfloat16(v);
    } else if (idx < WB_OFF + WB_ELEMS) {
        int r = idx - WB_OFF, taps; const float* w;
        if (r < 122880)       { taps = 1; w = w1; }
        else if (r < 368640)  { taps = 2; w = w2; r -= 122880; }
        else if (r < 737280)  { taps = 3; w = w3; r -= 368640; }
        else                  { taps = 7; w = w7; r -= 737280; }
        int e    = r & 7;
        int lane = (r >> 3) & 63;
        int f    = (r >> 9) & 15;
        int rt   = r >> 13;              // (mt*5+ch)*taps + t
        int t    = rt % taps;
        int mc   = rt / taps;
        int ch   = mc % 5;
        int mt   = mc / 5;
        int ks = f >> 2, mq = f & 3;
        int m = mt * 128 + mq * 32 + (lane & 31);
        int c = ch * 64 + ks * 16 + (lane >> 5) * 8 + e;
        float v = (m < Cn && c < Cn) ? w[(m * Cn + c) * taps + t] : 0.f;
        wsb[idx] = __float2bfloat16(v);
    } else if (idx < WC_OFF + WC_ELEMS) {
        int r = idx - WC_OFF;
        int e    = r & 7;
        int lane = (r >> 3) & 63;
        int f    = (r >> 9) & 15;
        int mc   = r >> 13;
        int ch   = mc % 19;
        int mt4  = mc / 19;
        int ks = f >> 2, mq = f & 3;
        int h = mt4 * 128 + mq * 32 + (lane & 31);
        int k = ch * 64 + ks * 16 + (lane >> 5) * 8 + e;   // 0..1215
        int cid = k / 304;
        int mk  = k - cid * 304;
        const float* row = slp_w + h * 1500;
        float v = 0.f;
        if (mk < 300) {
            if (cid == 0)      v = row[mk];
            else if (cid == 1) v = row[300 + mk];
            else if (cid == 2) v = row[600 + mk] + row[900 + mk];   // x3 + x5 fold
            else               v = row[1200 + mk];
        }
        wsb[idx] = __float2bfloat16(v);
    }
}

#define MFMA __builtin_amdgcn_mfma_f32_32x32x16_bf16

// ---------------- conv GEMM body ----------------
// block tile 128n x 128m; wave tile 64n x 64m (acc 2x2). A = weights (frag-major from
// global, register double-buffered); B = x (LDS, double-buffered, supports tap shifts).
// Epilogue writes hbuf in B-frag-major layout for the linear kernel (8B vector stores).
template<int TAPS, int LEAD>
__device__ __forceinline__ void conv_body(
        const short* __restrict__ xbs, const short* __restrict__ wsp,
        const float* __restrict__ bias, int cid, int mt, int nt,
        short* __restrict__ hbuf, short* xs) {
    const int tid  = threadIdx.x;
    const int lane = tid & 63;
    const int wave = tid >> 6;
    const int wn = wave & 1, wm = wave >> 1;
    const int lr = lane & 31;
    const int lk = (lane >> 5) << 3;
    const int TRIG = (TAPS >= 3) ? TAPS - 2 : 0;

    floatx16 acc[2][2];   // [mi][ni]
#pragma unroll
    for (int i = 0; i < 2; i++)
#pragma unroll
        for (int j = 0; j < 2; j++)
#pragma unroll
            for (int r = 0; r < 16; r++) acc[i][j][r] = 0.f;

    short8 wA[8], wB[8], st[5];

    // prologue: stage chunk 0 + preload stage(0,0) w-frags
#pragma unroll
    for (int i = 0; i < 5; ++i) {
        int j = tid + 256 * i;
        if (i < 4 || j < 1072)
            st[i] = *(const short8*)&xbs[(j >> 3) * XBC + ((j & 7) << 3)];
    }
#pragma unroll
    for (int ks = 0; ks < 4; ++ks)
#pragma unroll
        for (int mf = 0; mf < 2; ++mf)
            wA[ks * 2 + mf] = *(const short8*)&wsp[(ks * 4 + wm * 2 + mf) * 512 + lane * 8];
#pragma unroll
    for (int i = 0; i < 5; ++i) {
        int j = tid + 256 * i;
        if (i < 4 || j < 1072)
            *(short8*)&xs[(j >> 3) * LDSTC + ((j & 7) << 3)] = st[i];
    }
    __syncthreads();

    for (int c5 = 0; c5 < 5; ++c5) {
        const short* cur = xs + (c5 & 1) * XSZ;
        short* nxt = xs + ((c5 + 1) & 1) * XSZ;
        const int c0n = (c5 + 1) * 64;
#pragma unroll
        for (int t = 0; t < TAPS; ++t) {
            if (!(c5 == 4 && t == TAPS - 1)) {       // prefetch next stage's A(w) frags
                const short* wtn = (t + 1 < TAPS) ? wsp + (c5 * TAPS + t + 1) * 8192
                                                  : wsp + ((c5 + 1) * TAPS) * 8192;
#pragma unroll
                for (int ks = 0; ks < 4; ++ks)
#pragma unroll
                    for (int mf = 0; mf < 2; ++mf)
                        wB[ks * 2 + mf] = *(const short8*)&wtn[(ks * 4 + wm * 2 + mf) * 512 + lane * 8];
            }
            if (t == TRIG && c5 < 4) {               // staging after this chunk's w-frags
#pragma unroll
                for (int i = 0; i < 5; ++i) {
                    int j = tid + 256 * i;
                    if (i < 4 || j < 1072)
                        st[i] = *(const short8*)&xbs[(j >> 3) * XBC + c0n + ((j & 7) << 3)];
                }
            }
            const int sh = t - LEAD + 3;
            const int br = (wn * 64 + lr + sh) * LDSTC + lk;
#pragma unroll
            for (int ks = 0; ks < 4; ++ks) {
                short8 x0 = *(const short8*)&cur[br + ks * 16];
                short8 x1 = *(const short8*)&cur[br + 32 * LDSTC + ks * 16];
                acc[0][0] = MFMA(wA[ks * 2 + 0], x0, acc[0][0], 0, 0, 0);
                acc[0][1] = MFMA(wA[ks * 2 + 0], x1, acc[0][1], 0, 0, 0);
                acc[1][0] = MFMA(wA[ks * 2 + 1], x0, acc[1][0], 0, 0, 0);
                acc[1][1] = MFMA(wA[ks * 2 + 1], x1, acc[1][1], 0, 0, 0);
            }
            if (!(c5 == 4 && t == TAPS - 1)) {
#pragma unroll
                for (int f = 0; f < 8; ++f) wA[f] = wB[f];
            }
        }
        if (c5 < 4) {
#pragma unroll
            for (int i = 0; i < 5; ++i) {
                int j = tid + 256 * i;
                if (i < 4 || j < 1072)
                    *(short8*)&nxt[(j >> 3) * LDSTC + ((j & 7) << 3)] = st[i];
            }
        }
        __syncthreads();
    }

    // epilogue: D rows = m (regs), cols = n (lane&31). Write frag-major hbuf:
    // idx(n,k) = ((n>>5)*76 + (k>>4))*512 + ((n&31) + 32*((k>>3)&1))*8 + (k&7)
#pragma unroll
    for (int mi = 0; mi < 2; ++mi)
#pragma unroll
        for (int ni = 0; ni < 2; ++ni) {
            floatx16 v = acc[mi][ni];
            const int n5 = nt * 4 + wn * 2 + ni;
#pragma unroll
            for (int q = 0; q < 4; ++q) {
                int mb = mt * 128 + wm * 64 + mi * 32 + q * 8 + ((lane >> 5) << 2);
                if (mb < Cn) {
                    float4 bv = *(const float4*)&bias[mb];
                    short4v pk;
                    pk[0] = ((__hip_bfloat16_raw)__float2bfloat16(fast_tanh(v[q*4+0] + bv.x))).x;
                    pk[1] = ((__hip_bfloat16_raw)__float2bfloat16(fast_tanh(v[q*4+1] + bv.y))).x;
                    pk[2] = ((__hip_bfloat16_raw)__float2bfloat16(fast_tanh(v[q*4+2] + bv.z))).x;
                    pk[3] = ((__hip_bfloat16_raw)__float2bfloat16(fast_tanh(v[q*4+3] + bv.w))).x;
                    int k0  = cid * 304 + mb;
                    int off = (n5 * 76 + (k0 >> 4)) * 512 + (lr + ((q & 1) << 5)) * 8 + ((lane >> 5) << 2);
                    *(short4v*)&hbuf[off] = pk;
                }
            }
        }
}

// grid (128 n-tiles of 128, 12 y; heavy convs first)
__global__ __launch_bounds__(256, 2) void conv_kernel(
        const __hip_bfloat16* __restrict__ xbg, const __hip_bfloat16* __restrict__ Wbg,
        const float* __restrict__ bias1, const float* __restrict__ bias2,
        const float* __restrict__ bias3, const float* __restrict__ bias7,
        __hip_bfloat16* __restrict__ hbuf) {
    __shared__ __align__(16) short xs[2 * XSZ];

    const int nt = blockIdx.x;
    const int my = blockIdx.y;
    const int g  = my / 3;                   // 0:conv7 1:conv3 2:conv2 3:conv1
    const int mt = my % 3;

    const int b  = nt >> 2;
    const int l0 = (nt & 3) << 7;
    const short* xbs = (const short*)xbg + (b * XBP + l0) * XBC;
    const short* wb  = (const short*)Wbg;
    short* hb = (short*)hbuf;

    if (g == 0)      conv_body<7, 3>(xbs, wb + 737280 + mt * 7 * 40960, bias7, 3, mt, nt, hb, xs);
    else if (g == 1) conv_body<3, 1>(xbs, wb + 368640 + mt * 3 * 40960, bias3, 2, mt, nt, hb, xs);
    else if (g == 2) conv_body<2, 0>(xbs, wb + 122880 + mt * 2 * 40960, bias2, 1, mt, nt, hb, xs);
    else             conv_body<1, 0>(xbs, wb +      0 + mt * 1 * 40960, bias1, 0, mt, nt, hb, xs);
}

// ---------------- linear GEMM ----------------
// Barrier-free, LDS-free frag streaming. Block = 4 waves sharing one 64-row n-tile
// (h-frags L1-shared); wave tile 64h x 64n (acc 2x2). 19 chunks fully unrolled,
// ping-pong register buffers, loads issued one chunk ahead (vmcnt never drains).
__global__ __launch_bounds__(256, 2) void linear_kernel(
        const __hip_bfloat16* __restrict__ hbufg, const __hip_bfloat16* __restrict__ Wcg,
        const float* __restrict__ slp_b, float* __restrict__ out) {
    const int tid  = threadIdx.x;
    const int lane = tid & 63;
    const int wave = tid >> 6;
    const int lr   = lane & 31;

    const int nt64 = blockIdx.x;                 // 0..255
    const int hw   = blockIdx.y * 4 + wave;      // 0..7
    const int mt4  = hw >> 1;
    const int mq0  = (hw & 1) * 2;

    const short* hb = (const short*)hbufg;
    const short* wc = (const short*)Wcg;

    floatx16 acc[2][2];   // [mi][ni]
#pragma unroll
    for (int i = 0; i < 2; i++)
#pragma unroll
        for (int j = 0; j < 2; j++)
#pragma unroll
            for (int r = 0; r < 16; r++) acc[i][j][r] = 0.f;

    short8 wf[2][8], hf[2][8];

#define LOAD_CHUNK(ch, p)                                                                 \
    {                                                                                     \
        _Pragma("unroll")                                                                 \
        for (int ks = 0; ks < 4; ++ks)                                                    \
            _Pragma("unroll")                                                             \
            for (int ni = 0; ni < 2; ++ni)                                                \
                hf[p][ks * 2 + ni] = *(const short8*)                                     \
                    &hb[(((nt64 * 2 + ni) * 76) + (ch) * 4 + ks) * 512 + lane * 8];       \
        _Pragma("unroll")                                                                 \
        for (int ks = 0; ks < 4; ++ks)                                                    \
            _Pragma("unroll")                                                             \
            for (int mi = 0; mi < 2; ++mi)                                                \
                wf[p][ks * 2 + mi] = *(const short8*)                                     \
                    &wc[((mt4 * 19 + (ch)) * 16 + ks * 4 + mq0 + mi) * 512 + lane * 8];   \
    }

    LOAD_CHUNK(0, 0)
#pragma unroll
    for (int ch = 0; ch < 19; ++ch) {
        const int p = ch & 1;
        if (ch < 18) LOAD_CHUNK(ch + 1, p ^ 1)
#pragma unroll
        for (int ks = 0; ks < 4; ++ks) {
            acc[0][0] = MFMA(wf[p][ks * 2 + 0], hf[p][ks * 2 + 0], acc[0][0], 0, 0, 0);
            acc[0][1] = MFMA(wf[p][ks * 2 + 0], hf[p][ks * 2 + 1], acc[0][1], 0, 0, 0);
            acc[1][0] = MFMA(wf[p][ks * 2 + 1], hf[p][ks * 2 + 0], acc[1][0], 0, 0, 0);
            acc[1][1] = MFMA(wf[p][ks * 2 + 1], hf[p][ks * 2 + 1], acc[1][1], 0, 0, 0);
        }
    }
#undef LOAD_CHUNK

    // D rows = h (regs), cols = n (lane&31): float4 stores (h fastest dim of out)
#pragma unroll
    for (int mi = 0; mi < 2; ++mi)
#pragma unroll
        for (int ni = 0; ni < 2; ++ni) {
            floatx16 v = acc[mi][ni];
            const int n = nt64 * 64 + ni * 32 + lr;
#pragma unroll
            for (int q = 0; q < 4; ++q) {
                int h0 = hw * 64 + mi * 32 + q * 8 + ((lane >> 5) << 2);
                float4 bv = *(const float4*)&slp_b[h0];
                float4 o;
                o.x = fast_tanh(v[q * 4 + 0] + bv.x);
                o.y = fast_tanh(v[q * 4 + 1] + bv.y);
                o.z = fast_tanh(v[q * 4 + 2] + bv.z);
                o.w = fast_tanh(v[q * 4 + 3] + bv.w);
                *(float4*)&out[n * Hn + h0] = o;
            }
        }
}

// ---------------- launch ----------------

extern "C" void kernel_launch(void* const* d_in, const int* in_sizes, int n_in,
                              void* d_out, int out_size, void* d_ws, size_t ws_size,
                              hipStream_t stream) {
    const float* x     = (const float*)d_in[0];
    const float* w1    = (const float*)d_in[1];
    const float* b1    = (const float*)d_in[2];
    const float* w2    = (const float*)d_in[3];
    const float* b2    = (const float*)d_in[4];
    const float* w3    = (const float*)d_in[5];
    const float* b3    = (const float*)d_in[6];
    const float* w7    = (const float*)d_in[7];
    const float* b7    = (const float*)d_in[8];
    const float* slp_w = (const float*)d_in[9];
    const float* slp_b = (const float*)d_in[10];

    __hip_bfloat16* wsb = (__hip_bfloat16*)d_ws;

    const int prep_total = XB_ELEMS + WB_ELEMS + WC_ELEMS;   // 7,524,352
    prep_all<<<(prep_total + 255) / 256, 256, 0, stream>>>(x, w1, w2, w3, w7, slp_w, wsb);

    conv_kernel<<<dim3(128, 12), 256, 0, stream>>>(wsb + XB_OFF, wsb + WB_OFF,
                                                   b1, b2, b3, b7, wsb + HB_OFF);
    linear_kernel<<<dim3(256, 2), 256, 0, stream>>>(wsb + HB_OFF, wsb + WC_OFF,
                                                    slp_b, (float*)d_out);
}